// Round 9
// baseline (4532.161 us; speedup 1.0000x reference)
//
#include <hip/hip_runtime.h>
#include <math.h>

#define NN 32768
#define HH 128
#define DD 16
#define BB 256
#define E2N (NN*DD)
#define NF (NN*HH)

typedef __attribute__((ext_vector_type(8))) short bf16x8;
typedef __attribute__((ext_vector_type(4))) short bf16x4;
typedef __attribute__((ext_vector_type(4))) float f32x4;

__device__ __forceinline__ float fsig(float x) { return 1.0f/(1.0f + __expf(-x)); }
__device__ __forceinline__ float ftanh(float x) {
  float cx = fminf(fmaxf(x, -15.0f), 15.0f);
  float e = __expf(2.0f*cx);
  return 1.0f - 2.0f/(e + 1.0f);
}

// round-to-nearest-even fp32 -> bf16 (top 16 bits)
__device__ __forceinline__ unsigned bf16_rne(float x) {
  unsigned u = __float_as_uint(x);
  return (u + 0x7FFFu + ((u >> 16) & 1u)) >> 16;
}
__device__ __forceinline__ void bsplit(float x, short& hi, short& lo) {
  unsigned hb = bf16_rne(x);
  float hf = __uint_as_float(hb << 16);
  hi = (short)hb;
  lo = (short)bf16_rne(x - hf);
}

// ---------------- transpose prep (weights -> [K][Nout] layout) ----------------
struct TDesc { const float* src; float* dst; int R; int C; };
struct TDescArr { TDesc d[26]; };

__global__ void transpose_many(TDescArr da) {
  TDesc t = da.d[blockIdx.y];
  int idx = blockIdx.x*256 + threadIdx.x;
  if (idx < t.R*t.C) {
    int r = idx / t.C, c = idx - r*t.C;
    t.dst[(size_t)c*t.R + r] = t.src[idx];
  }
}

__global__ void bias_sum_kernel(const float* __restrict__ bih, const float* __restrict__ bhh,
                                float* __restrict__ bsum) {
  int i = blockIdx.x*256 + threadIdx.x;
  if (i < 2048) bsum[i] = bih[i] + bhh[i];
}

// split 4 matrices [512][128] fp32 -> bf16 hi/lo (same layout)
__global__ void wsplit_kernel(const float* __restrict__ W,
                              short* __restrict__ hi, short* __restrict__ lo) {
  int i = blockIdx.x*256 + threadIdx.x;   // 4*512*128 elems
  short h, l;
  bsplit(W[i], h, l);
  hi[i] = h; lo[i] = l;
}

// ---------------- embeddings ----------------
__global__ void embed3_kernel(const int* __restrict__ a_ids, const int* __restrict__ d_ids,
                              const int* __restrict__ a2_ids,
                              const float* __restrict__ ea, const float* __restrict__ ed,
                              const float* __restrict__ ea2,
                              float* __restrict__ ha, float* __restrict__ hd,
                              float* __restrict__ hg2) {
  int idx = blockIdx.x*256 + threadIdx.x;
  int n = idx >> 7, j = idx & 127;
  int w = blockIdx.y;
  if (w == 0)      ha[idx]  = ea[(size_t)a_ids[n]*128 + j];
  else if (w == 1) hd[idx]  = ed[(size_t)d_ids[n]*128 + j];
  else             hg2[idx] = ea2[(size_t)a2_ids[n]*128 + j];
}

// ---------------- generic GEMM: C = act(A @ W^T + bias + beta*C) ----------------
template<int BN, int ACT>
__global__ __launch_bounds__(256) void gemm_nt(
    const float* __restrict__ A0, const float* __restrict__ A1,
    const float* __restrict__ A2, const float* __restrict__ A3,
    int lda, const float* __restrict__ WT, const float* __restrict__ bias,
    float* __restrict__ C, int K, int beta)
{
  extern __shared__ float sm[];
  const int KP = K + 4;
  float* At = sm;             // [32][KP]
  float* Bc = sm + 32*KP;     // [16][BN]
  const int tid = threadIdx.x;
  const int m0 = blockIdx.x*32;
  const int ng = tid >> 5, cg = tid & 31;
  const int n0 = ng*4, c4 = cg*4;
  constexpr int G = BN/128;
  float acc[G][4][4];
#pragma unroll
  for (int g=0; g<G; ++g)
#pragma unroll
    for (int i=0;i<4;++i)
#pragma unroll
      for (int e=0;e<4;++e) acc[g][i][e] = 0.0f;

  const int nf4 = K >> 2;
  for (int idx = tid; idx < 32*nf4; idx += 256) {
    int row = idx / nf4;
    int kk = (idx - row*nf4) << 2;
    const float* Ap = (kk < 128) ? A0 : (kk < 256) ? A1 : (kk < 384) ? A2 : A3;
    float4 v = *(const float4*)(Ap + (size_t)(m0+row)*lda + (kk & 127));
    *(float4*)(At + row*KP + kk) = v;
  }
  const int nchunk = K >> 4;
  for (int kc = 0; kc < nchunk; ++kc) {
    __syncthreads();
    for (int idx = tid; idx < 16*(BN/4); idx += 256) {
      int kk = idx / (BN/4);
      int jq = idx - kk*(BN/4);
      *(float4*)(Bc + kk*BN + jq*4) = *(const float4*)(WT + (size_t)(kc*16+kk)*BN + jq*4);
    }
    __syncthreads();
    for (int k=0;k<16;++k) {
      const int kk = kc*16 + k;
      float av[4];
#pragma unroll
      for (int i=0;i<4;++i) av[i] = At[(n0+i)*KP + kk];
#pragma unroll
      for (int g=0; g<G; ++g) {
        float4 bv = *(const float4*)(Bc + k*BN + g*128 + c4);
        float bb[4] = {bv.x, bv.y, bv.z, bv.w};
#pragma unroll
        for (int i=0;i<4;++i)
#pragma unroll
          for (int e=0;e<4;++e)
            acc[g][i][e] += av[i]*bb[e];
      }
    }
  }
#pragma unroll
  for (int g=0; g<G; ++g) {
#pragma unroll
    for (int i=0;i<4;++i) {
      float* dst = C + (size_t)(m0+n0+i)*BN + g*128 + c4;
      float o[4];
#pragma unroll
      for (int e=0;e<4;++e) o[e] = acc[g][i][e];
      if (bias) {
#pragma unroll
        for (int e=0;e<4;++e) o[e] += bias[g*128 + c4 + e];
      }
      if (beta) {
        float4 p = *(const float4*)dst;
        o[0]+=p.x; o[1]+=p.y; o[2]+=p.z; o[3]+=p.w;
      }
      if (ACT==1) {
#pragma unroll
        for (int e=0;e<4;++e) o[e] = fmaxf(o[e], 0.0f);
      }
      *(float4*)dst = make_float4(o[0],o[1],o[2],o[3]);
    }
  }
}

// ---------------- Gx precompute via MFMA: Gx[row][512] = Wih . fs[row] + bsum ----------------
// One direction per launch (512 blocks x 64 rows). Output table = 64 MB -> L3-resident.
__global__ __launch_bounds__(512) void gx_kernel(
    float* __restrict__ Gx, const float* __restrict__ fs,
    const short* __restrict__ WIhi, const short* __restrict__ WIlo,
    const float* __restrict__ bsum)
{
  __shared__ short xhi[64*136];
  __shared__ short xlo[64*136];
  const int tid = threadIdx.x;
  const int w = tid >> 6;
  const int lane = tid & 63;
  const int ln16 = lane & 15;
  const int lq = lane >> 4;
  const int rb = blockIdx.x * 64;

  {
    const int r = tid >> 3;
    const int cf = (tid & 7) * 16;
    const float* src = fs + (size_t)(rb + r)*128 + cf;
    short* dh = xhi + r*136 + cf;
    short* dl = xlo + r*136 + cf;
#pragma unroll
    for (int q=0; q<4; ++q) {
      float4 v = *(const float4*)(src + q*4);
      float vs[4] = {v.x, v.y, v.z, v.w};
      bf16x4 sh, sl;
#pragma unroll
      for (int e=0;e<4;++e){ short h_,l_; bsplit(vs[e],h_,l_); sh[e]=h_; sl[e]=l_; }
      *(bf16x4*)(dh + q*4) = sh;
      *(bf16x4*)(dl + q*4) = sl;
    }
  }
  f32x4 acc[4][4];   // [gate][nt]
#pragma unroll
  for (int g=0; g<4; ++g) {
    f32x4 bv = *(const f32x4*)(bsum + g*128 + w*16 + lq*4);
#pragma unroll
    for (int nt=0; nt<4; ++nt) acc[g][nt] = bv;
  }
  __syncthreads();

#pragma unroll
  for (int kt=0; kt<4; ++kt) {
    const int bo = kt*32 + lq*8;
    bf16x8 bxh[4], bxl[4];
#pragma unroll
    for (int nt=0; nt<4; ++nt) {
      bxh[nt] = *(const bf16x8*)(xhi + (nt*16+ln16)*136 + bo);
      bxl[nt] = *(const bf16x8*)(xlo + (nt*16+ln16)*136 + bo);
    }
#pragma unroll
    for (int g=0; g<4; ++g) {
      const int co = (g*128 + w*16 + ln16)*128 + kt*32 + lq*8;
      bf16x8 ah = *(const bf16x8*)(WIhi + co);
      bf16x8 al = *(const bf16x8*)(WIlo + co);
#pragma unroll
      for (int nt=0; nt<4; ++nt) {
        acc[g][nt] = __builtin_amdgcn_mfma_f32_16x16x32_bf16(ah, bxh[nt], acc[g][nt], 0,0,0);
        acc[g][nt] = __builtin_amdgcn_mfma_f32_16x16x32_bf16(ah, bxl[nt], acc[g][nt], 0,0,0);
        acc[g][nt] = __builtin_amdgcn_mfma_f32_16x16x32_bf16(al, bxh[nt], acc[g][nt], 0,0,0);
      }
    }
  }
#pragma unroll
  for (int nt=0; nt<4; ++nt) {
    const size_t row = (size_t)(rb + nt*16 + ln16);
#pragma unroll
    for (int g=0; g<4; ++g) {
      f32x4 v = acc[g][nt];
      *(float4*)(Gx + row*512 + g*128 + w*16 + lq*4) =
          make_float4(v[0], v[1], v[2], v[3]);
    }
  }
}

// ---------------- LSTM recurrence (one direction per launch) ----------------
// 1024 blocks x 32 nodes, 4 waves. Gather table = one 64 MB Gx half (L3-resident).
// Decoupled gather (gxv) + zero-init racc MFMA chain; indices prefetched.
__global__ __launch_bounds__(256) void lstm_seq_kernel(
    float* __restrict__ hL, const float* __restrict__ Gx,
    const int* __restrict__ nbr,
    const short* __restrict__ WHhi, const short* __restrict__ WHlo)
{
  __shared__ short hhi[32*136];
  __shared__ short hlo[32*136];
  const int tid = threadIdx.x;
  const int w = tid >> 6;          // wave 0..3
  const int lane = tid & 63;
  const int ln16 = lane & 15;
  const int lq = lane >> 4;
  const int nb = blockIdx.x * 32;

  f32x4 gxv[4][2][2];   // gathered pre-activations (in flight during MFMA)
  f32x4 cst[2][2];
#pragma unroll
  for (int p=0;p<2;++p)
#pragma unroll
    for (int nt=0;nt<2;++nt)
#pragma unroll
      for (int e=0;e<4;++e) cst[p][nt][e] = 0.0f;

  const int* nrow0 = nbr + (size_t)(nb + ln16)*DD;
  const int* nrow1 = nbr + (size_t)(nb + 16 + ln16)*DD;
  int gidx0 = nrow0[0], gidx1 = nrow1[0];

#pragma unroll 1
  for (int t=0; t<16; ++t) {
    // ---- (1) issue gathers into gxv (independent of MFMA chain) ----
    {
      const float* r0 = Gx + (size_t)gidx0*512 + w*32 + lq*4;
      const float* r1 = Gx + (size_t)gidx1*512 + w*32 + lq*4;
#pragma unroll
      for (int g=0; g<4; ++g)
#pragma unroll
        for (int p=0; p<2; ++p) {
          gxv[g][p][0] = *(const f32x4*)(r0 + g*128 + p*16);
          gxv[g][p][1] = *(const f32x4*)(r1 + g*128 + p*16);
        }
    }
    if (t < 15) { gidx0 = nrow0[t+1]; gidx1 = nrow1[t+1]; }

    // ---- (2) recurrent term into zero-init racc ----
    f32x4 racc[4][2][2];
#pragma unroll
    for (int g=0;g<4;++g)
#pragma unroll
      for (int p=0;p<2;++p)
#pragma unroll
        for (int nt=0;nt<2;++nt)
#pragma unroll
          for (int e=0;e<4;++e) racc[g][p][nt][e] = 0.0f;
    if (t > 0) {
#pragma unroll
      for (int kt=0; kt<4; ++kt) {
        const int bo = kt*32 + lq*8;
        bf16x8 bh[2], bl[2];
#pragma unroll
        for (int nt=0; nt<2; ++nt) {
          bh[nt] = *(const bf16x8*)(hhi + (nt*16+ln16)*136 + bo);
          bl[nt] = *(const bf16x8*)(hlo + (nt*16+ln16)*136 + bo);
        }
#pragma unroll
        for (int g=0; g<4; ++g) {
#pragma unroll
          for (int p=0; p<2; ++p) {
            const int co = (g*128 + w*32 + p*16 + ln16)*128 + kt*32 + lq*8;
            bf16x8 ah = *(const bf16x8*)(WHhi + co);
            bf16x8 al = *(const bf16x8*)(WHlo + co);
#pragma unroll
            for (int nt=0; nt<2; ++nt) {
              racc[g][p][nt] = __builtin_amdgcn_mfma_f32_16x16x32_bf16(ah, bh[nt], racc[g][p][nt], 0,0,0);
              racc[g][p][nt] = __builtin_amdgcn_mfma_f32_16x16x32_bf16(ah, bl[nt], racc[g][p][nt], 0,0,0);
              racc[g][p][nt] = __builtin_amdgcn_mfma_f32_16x16x32_bf16(al, bh[nt], racc[g][p][nt], 0,0,0);
            }
          }
        }
      }
    }
    __syncthreads();   // all h(t-1) LDS reads done (WAR)

    // ---- (3) activations: pre = gxv + racc ----
#pragma unroll
    for (int p=0; p<2; ++p) {
#pragma unroll
      for (int nt=0; nt<2; ++nt) {
        float hv[4];
#pragma unroll
        for (int e=0; e<4; ++e) {
          float ig = fsig(gxv[0][p][nt][e] + racc[0][p][nt][e]);
          float fg = fsig(gxv[1][p][nt][e] + racc[1][p][nt][e]);
          float gg = ftanh(gxv[2][p][nt][e] + racc[2][p][nt][e]);
          float og = fsig(gxv[3][p][nt][e] + racc[3][p][nt][e]);
          float cc = fg*cst[p][nt][e] + ig*gg;
          cst[p][nt][e] = cc;
          hv[e] = og*ftanh(cc);
        }
        const int node = nt*16 + ln16;
        const int col0 = w*32 + p*16 + lq*4;
        if (t < 15) {
          bf16x4 sh, sl;
#pragma unroll
          for (int e=0; e<4; ++e) { short h_,l_; bsplit(hv[e],h_,l_); sh[e]=h_; sl[e]=l_; }
          *(bf16x4*)(hhi + node*136 + col0) = sh;
          *(bf16x4*)(hlo + node*136 + col0) = sl;
        } else {
          *(float4*)(hL + (size_t)(nb + node)*128 + col0) =
              make_float4(hv[0], hv[1], hv[2], hv[3]);
        }
      }
    }
    __syncthreads();   // h(t) writes visible before next step's reads (RAW)
  }
}

// ---------------- GGC scatter-add: a[dst] += m[src] (128 floats/edge) ----------------
__global__ void scatter_add_kernel(float* __restrict__ a, const float* __restrict__ m,
                                   const int* __restrict__ src, const int* __restrict__ dst) {
  int wid = (blockIdx.x*256 + threadIdx.x) >> 6;
  int lane = threadIdx.x & 63;
  int s = src[wid], d = dst[wid];
  const float* mr = m + (size_t)s*128;
  float* ar = a + (size_t)d*128;
  atomicAdd(ar + lane, mr[lane]);
  atomicAdd(ar + 64 + lane, mr[64 + lane]);
}

// ---------------- GRU pointwise ----------------
__global__ void gru_update_kernel(float* __restrict__ hh, const float* __restrict__ gi,
                                  const float* __restrict__ gh) {
  int idx = blockIdx.x*256 + threadIdx.x;
  int n = idx >> 7, j = idx & 127;
  const float* gin = gi + (size_t)n*384;
  const float* ghn = gh + (size_t)n*384;
  float r  = fsig(gin[j] + ghn[j]);
  float z  = fsig(gin[128+j] + ghn[128+j]);
  float nn2 = ftanh(gin[256+j] + r*ghn[256+j]);
  float h = hh[idx];
  hh[idx] = (1.0f - z)*nn2 + z*h;
}

// ---------------- LayerNorm (+optional residual add) + leaky relu ----------------
__global__ void ln_lrelu_kernel(float* __restrict__ out, const float* __restrict__ x,
                                const float* __restrict__ add,
                                const float* __restrict__ g, const float* __restrict__ b) {
  int n = blockIdx.x, j = threadIdx.x;   // 128 threads
  size_t base = (size_t)n*128;
  float v = x[base+j];
  if (add) v += add[base+j];
  __shared__ float sh[4];
  float s = v;
#pragma unroll
  for (int m=32; m>=1; m>>=1) s += __shfl_xor(s, m, 64);
  if ((j&63)==0) sh[j>>6] = s;
  __syncthreads();
  float mean = (sh[0]+sh[1]) * 0.0078125f;
  float d = v - mean;
  float q = d*d;
#pragma unroll
  for (int m=32; m>=1; m>>=1) q += __shfl_xor(q, m, 64);
  if ((j&63)==0) sh[2+(j>>6)] = q;
  __syncthreads();
  float var = (sh[2]+sh[3]) * 0.0078125f;
  float y = d * rsqrtf(var + 1e-5f) * g[j] + b[j];
  out[base+j] = (y >= 0.0f) ? y : 0.01f*y;
}

// ---------------- segment mean (contiguous 128-node segments) ----------------
__global__ void segmean_kernel(float* __restrict__ out, const float* __restrict__ x,
                               const float* __restrict__ y) {
  int b = blockIdx.x, j = threadIdx.x;   // 128 threads, 256 blocks
  float s = 0.0f;
  for (int r=0; r<128; ++r) {
    size_t n = (size_t)(b*128 + r)*128 + j;
    s += x[n];
    if (y) s += y[n];
  }
  out[(size_t)b*128 + j] = s * 0.0078125f;
}

// ---------------- classifier head ----------------
__global__ void cls_kernel(float* __restrict__ out, const float* __restrict__ h2,
                           const float* __restrict__ Wc, const float* __restrict__ bc) {
  int gid = blockIdx.x*256 + threadIdx.x;
  if (gid >= BB*10) return;
  int mrow = gid/10, c = gid - mrow*10;
  const float* arow = h2 + (size_t)mrow*128;
  const float* wrow = Wc + (size_t)c*128;
  float s = bc[c];
  for (int k=0;k<128;++k) s += arow[k]*wrow[k];
  out[gid] = s;
}

__global__ void bail_kernel(float* out, float v) {
  if (threadIdx.x==0 && blockIdx.x==0) out[0] = v;
}

// ---------------- host orchestration ----------------
extern "C" void kernel_launch(void* const* d_in, const int* in_sizes, int n_in,
                              void* d_out, int out_size, void* d_ws, size_t ws_size,
                              hipStream_t stream)
{
  const int* act_ids  = (const int*)d_in[0];
  const int* dur_ids  = (const int*)d_in[1];
  const int* act2_ids = (const int*)d_in[2];
  const int* nbr_a2d  = (const int*)d_in[3];
  const int* nbr_d2a  = (const int*)d_in[4];
  const int* src2     = (const int*)d_in[5];
  const int* dst2     = (const int*)d_in[6];
  const float* emb_act     = (const float*)d_in[8];
  const float* emb_dur     = (const float*)d_in[9];
  const float* emb_act2    = (const float*)d_in[10];
  const float* transform_W = (const float*)d_in[11];
  const float* transform_b = (const float*)d_in[12];
  const float* ggc_W   = (const float*)d_in[13];
  const float* ggc_b   = (const float*)d_in[14];
  const float* gru_Wih = (const float*)d_in[15];
  const float* gru_Whh = (const float*)d_in[16];
  const float* gru_bih = (const float*)d_in[17];
  const float* gru_bhh = (const float*)d_in[18];
  const float* hn_g    = (const float*)d_in[19];
  const float* hn_b    = (const float*)d_in[20];
  const float* lstm_Wih = (const float*)d_in[21];
  const float* lstm_Whh = (const float*)d_in[22];
  const float* lstm_bih = (const float*)d_in[23];
  const float* lstm_bhh = (const float*)d_in[24];
  const float* fcs_W = (const float*)d_in[25];
  const float* fcs_b = (const float*)d_in[26];
  const float* fcn_W = (const float*)d_in[27];
  const float* fcn_b = (const float*)d_in[28];
  const float* n1_g = (const float*)d_in[29];
  const float* n1_b = (const float*)d_in[30];
  const float* n3_g = (const float*)d_in[31];
  const float* n3_b = (const float*)d_in[32];
  const float* mh_W1 = (const float*)d_in[33];
  const float* mh_b1 = (const float*)d_in[34];
  const float* mh_W2 = (const float*)d_in[35];
  const float* mh_b2 = (const float*)d_in[36];
  const float* mo_W1 = (const float*)d_in[37];
  const float* mo_b1 = (const float*)d_in[38];
  const float* mo_W2 = (const float*)d_in[39];
  const float* mo_b2 = (const float*)d_in[40];
  const float* mlp_W1 = (const float*)d_in[41];
  const float* mlp_b1 = (const float*)d_in[42];
  const float* mlp_W2 = (const float*)d_in[43];
  const float* mlp_b2 = (const float*)d_in[44];
  const float* cls_W = (const float*)d_in[45];
  const float* cls_b = (const float*)d_in[46];

  float* ws = (float*)d_ws;
  float* ha   = ws;
  float* hd   = ws + (size_t)NF;
  float* hg2  = ws + 2*(size_t)NF;
  float* res  = ws + 3*(size_t)NF;
  float* hh   = ws + 4*(size_t)NF;
  float* SCR  = ws + 5*(size_t)NF;
  float* mb   = SCR;
  float* abuf = SCR + (size_t)NF;
  float* gi   = SCR + 2*(size_t)NF;
  float* gh   = SCR + 5*(size_t)NF;
  float* hnf  = mb;
  float* Gx   = SCR;                       // [N][512] fp32 = 4*NF floats (one dir at a time)
  float* hLb  = SCR + 8*(size_t)NF;
  float* SMALL = ws + 15*(size_t)NF;
  float* hg2m = SMALL;
  float* hgm  = SMALL + 32768;
  float* o1b  = SMALL + 65536;
  float* o2b  = SMALL + 98304;
  float* t1b  = SMALL + 131072;
  float* t2b  = SMALL + 163840;
  float* h1b  = SMALL + 196608;
  float* h2b  = SMALL + 262144;
  float* bsum = SMALL + 294912;
  float* WTb  = SMALL + 296960;
  const size_t NEED_BYTES = (size_t)(15*(size_t)NF + 296960 + 1032192) * 4;
  if (ws_size < NEED_BYTES) {
    hipMemsetAsync(d_out, 0, (size_t)out_size*sizeof(float), stream);
    bail_kernel<<<1,64,0,stream>>>((float*)d_out, (float)ws_size);
    return;
  }
  float* na = hg2;
  float* nd = res;

  const int O_TRANSFORM = 0;
  const int O_GGC      = 32768;
  const int O_GRUWIH   = 49152;
  const int O_GRUWHH   = 98304;
  const int O_SPLIT    = 147456;
  const int O_FCS      = 671744;
  const int O_FCN      = 737280;
  const int O_MH1      = 802816;
  const int O_MH2      = 819200;
  const int O_MO1      = 835584;
  const int O_MO2      = 851968;
  const int O_MLP1     = 868352;
  const int O_MLP2     = 999424;

  short* SPL = (short*)(WTb + O_SPLIT);
  short* WIhi = SPL;
  short* WIlo = SPL + 4*65536;
  short* WHhi = SPL + 8*65536;
  short* WHlo = SPL + 12*65536;

  TDescArr da;
  int di = 0;
  auto addT = [&](const float* s, float* d, int R, int C){ da.d[di].src=s; da.d[di].dst=d; da.d[di].R=R; da.d[di].C=C; ++di; };
  addT(transform_W, WTb + O_TRANSFORM, 128, 256);
  addT(ggc_W,   WTb + O_GGC,    128, 128);
  addT(gru_Wih, WTb + O_GRUWIH, 384, 128);
  addT(gru_Whh, WTb + O_GRUWHH, 384, 128);
  for (int i=0;i<4;++i) addT(fcs_W + (size_t)i*16384, WTb + O_FCS + i*16384, 128, 128);
  for (int i=0;i<4;++i) addT(fcn_W + (size_t)i*16384, WTb + O_FCN + i*16384, 128, 128);
  addT(mh_W1, WTb + O_MH1, 128, 128);
  addT(mh_W2, WTb + O_MH2, 128, 128);
  addT(mo_W1, WTb + O_MO1, 128, 128);
  addT(mo_W2, WTb + O_MO2, 128, 128);
  addT(mlp_W1, WTb + O_MLP1, 256, 512);
  addT(mlp_W2, WTb + O_MLP2, 128, 256);
  transpose_many<<<dim3(512, di), 256, 0, stream>>>(da);
  bias_sum_kernel<<<8, 256, 0, stream>>>(lstm_bih, lstm_bhh, bsum);
  wsplit_kernel<<<(4*512*128)/256, 256, 0, stream>>>(lstm_Wih, WIhi, WIlo);
  wsplit_kernel<<<(4*512*128)/256, 256, 0, stream>>>(lstm_Whh, WHhi, WHlo);

  auto smemK = [](int K, int BN){ return (size_t)(32*(K+4) + 16*BN)*4; };
  const int gN = NN/32;
  const int gB = BB/32;

  embed3_kernel<<<dim3(NF/256, 3), 256, 0, stream>>>(act_ids, dur_ids, act2_ids,
      emb_act, emb_dur, emb_act2, ha, hd, hg2);
  gemm_nt<128,0><<<gN, 256, smemK(256,128), stream>>>(hg2, hd, nullptr, nullptr, 128,
      WTb + O_TRANSFORM, transform_b, res, 256, 0);
  hipMemcpyAsync(hh, res, (size_t)NF*4, hipMemcpyDeviceToDevice, stream);

  for (int it=0; it<2; ++it) {
    gemm_nt<128,0><<<gN, 256, smemK(128,128), stream>>>(hh, nullptr, nullptr, nullptr, 128,
        WTb + O_GGC, ggc_b, mb, 128, 0);
    hipMemsetAsync(abuf, 0, (size_t)NF*4, stream);
    scatter_add_kernel<<<E2N/4, 256, 0, stream>>>(abuf, mb, src2, dst2);
    gemm_nt<384,0><<<gN, 256, smemK(128,384), stream>>>(abuf, nullptr, nullptr, nullptr, 128,
        WTb + O_GRUWIH, gru_bih, gi, 128, 0);
    gemm_nt<384,0><<<gN, 256, smemK(128,384), stream>>>(hh, nullptr, nullptr, nullptr, 128,
        WTb + O_GRUWHH, gru_bhh, gh, 128, 0);
    gru_update_kernel<<<NF/256, 256, 0, stream>>>(hh, gi, gh);
  }
  ln_lrelu_kernel<<<NN, 128, 0, stream>>>(hnf, hh, res, hn_g, hn_b);
  segmean_kernel<<<BB, 128, 0, stream>>>(hg2m, hnf, nullptr);

  for (int l=0; l<2; ++l) {
    const int i0 = l*2 + 0, i1 = l*2 + 1;
    // direction 0 (a2d): src feats = ha, table 64MB -> L3-resident
    gx_kernel<<<512, 512, 0, stream>>>(Gx, ha,
        WIhi + i0*65536, WIlo + i0*65536, bsum + i0*512);
    lstm_seq_kernel<<<1024, 256, 0, stream>>>(hLb, Gx, nbr_a2d,
        WHhi + i0*65536, WHlo + i0*65536);
    // direction 1 (d2a): src feats = hd (reuses the same Gx buffer)
    gx_kernel<<<512, 512, 0, stream>>>(Gx, hd,
        WIhi + i1*65536, WIlo + i1*65536, bsum + i1*512);
    lstm_seq_kernel<<<1024, 256, 0, stream>>>(hLb + (size_t)NN*128, Gx, nbr_d2a,
        WHhi + i1*65536, WHlo + i1*65536);

    gemm_nt<128,0><<<gN, 256, smemK(128,128), stream>>>(hd, nullptr, nullptr, nullptr, 128,
        WTb + O_FCS + i0*16384, fcs_b + i0*128, nd, 128, 0);
    gemm_nt<128,0><<<gN, 256, smemK(128,128), stream>>>(hLb, nullptr, nullptr, nullptr, 128,
        WTb + O_FCN + i0*16384, fcn_b + i0*128, nd, 128, 1);
    gemm_nt<128,0><<<gN, 256, smemK(128,128), stream>>>(ha, nullptr, nullptr, nullptr, 128,
        WTb + O_FCS + i1*16384, fcs_b + i1*128, na, 128, 0);
    gemm_nt<128,0><<<gN, 256, smemK(128,128), stream>>>(hLb + (size_t)NN*128, nullptr, nullptr, nullptr, 128,
        WTb + O_FCN + i1*16384, fcn_b + i1*128, na, 128, 1);
    ln_lrelu_kernel<<<NN, 128, 0, stream>>>(na, na, nullptr, n1_g + i0*128, n1_b + i0*128);
    ln_lrelu_kernel<<<NN, 128, 0, stream>>>(nd, nd, nullptr, n1_g + i1*128, n1_b + i1*128);
    ln_lrelu_kernel<<<NN, 128, 0, stream>>>(ha, ha, na, n3_g + i0*128, n3_b + i0*128);
    ln_lrelu_kernel<<<NN, 128, 0, stream>>>(hd, hd, nd, n3_g + i1*128, n3_b + i1*128);
  }
  segmean_kernel<<<BB, 128, 0, stream>>>(hgm, ha, hd);

  gemm_nt<128,1><<<gB, 256, smemK(128,128), stream>>>(hg2m, nullptr, nullptr, nullptr, 128,
      WTb + O_MO1, mo_b1, t1b, 128, 0);
  gemm_nt<128,1><<<gB, 256, smemK(128,128), stream>>>(t1b, nullptr, nullptr, nullptr, 128,
      WTb + O_MO2, mo_b2, o1b, 128, 0);
  gemm_nt<128,1><<<gB, 256, smemK(128,128), stream>>>(hgm, nullptr, nullptr, nullptr, 128,
      WTb + O_MH1, mh_b1, t2b, 128, 0);
  gemm_nt<128,1><<<gB, 256, smemK(128,128), stream>>>(t2b, nullptr, nullptr, nullptr, 128,
      WTb + O_MH2, mh_b2, o2b, 128, 0);
  gemm_nt<256,0><<<gB, 256, smemK(256,256), stream>>>(o1b, hg2m, nullptr, nullptr, 128,
      WTb + O_MLP1, nullptr, h1b, 256, 0);
  gemm_nt<256,1><<<gB, 256, smemK(256,256), stream>>>(o2b, hgm, nullptr, nullptr, 128,
      WTb + O_MLP1 + 256*256, mlp_b1, h1b, 256, 1);
  gemm_nt<128,1><<<gB, 256, smemK(256,128), stream>>>(h1b, h1b + 128, nullptr, nullptr, 256,
      WTb + O_MLP2, mlp_b2, h2b, 256, 0);
  cls_kernel<<<10, 256, 0, stream>>>((float*)d_out, h2b, cls_W, cls_b);
}

// Round 10
// 4325.780 us; speedup vs baseline: 1.0477x; 1.0477x over previous
//
#include <hip/hip_runtime.h>
#include <hip/hip_fp16.h>
#include <math.h>

#define NN 32768
#define HH 128
#define DD 16
#define BB 256
#define E2N (NN*DD)
#define NF (NN*HH)

typedef __attribute__((ext_vector_type(8))) short bf16x8;
typedef __attribute__((ext_vector_type(4))) short bf16x4;
typedef __attribute__((ext_vector_type(4))) float f32x4;
typedef __attribute__((ext_vector_type(4))) unsigned short u16x4;
typedef __attribute__((ext_vector_type(8))) unsigned short u16x8;

__device__ __forceinline__ float fsig(float x) { return 1.0f/(1.0f + __expf(-x)); }
__device__ __forceinline__ float ftanh(float x) {
  float cx = fminf(fmaxf(x, -15.0f), 15.0f);
  float e = __expf(2.0f*cx);
  return 1.0f - 2.0f/(e + 1.0f);
}

// round-to-nearest-even fp32 -> bf16 (top 16 bits)
__device__ __forceinline__ unsigned bf16_rne(float x) {
  unsigned u = __float_as_uint(x);
  return (u + 0x7FFFu + ((u >> 16) & 1u)) >> 16;
}
__device__ __forceinline__ void bsplit(float x, short& hi, short& lo) {
  unsigned hb = bf16_rne(x);
  float hf = __uint_as_float(hb << 16);
  hi = (short)hb;
  lo = (short)bf16_rne(x - hf);
}

// ---------------- transpose prep (weights -> [K][Nout] layout) ----------------
struct TDesc { const float* src; float* dst; int R; int C; };
struct TDescArr { TDesc d[26]; };

__global__ void transpose_many(TDescArr da) {
  TDesc t = da.d[blockIdx.y];
  int idx = blockIdx.x*256 + threadIdx.x;
  if (idx < t.R*t.C) {
    int r = idx / t.C, c = idx - r*t.C;
    t.dst[(size_t)c*t.R + r] = t.src[idx];
  }
}

__global__ void bias_sum_kernel(const float* __restrict__ bih, const float* __restrict__ bhh,
                                float* __restrict__ bsum) {
  int i = blockIdx.x*256 + threadIdx.x;
  if (i < 2048) bsum[i] = bih[i] + bhh[i];
}

// split 4 matrices [512][128] fp32 -> bf16 hi/lo (same layout)
__global__ void wsplit_kernel(const float* __restrict__ W,
                              short* __restrict__ hi, short* __restrict__ lo) {
  int i = blockIdx.x*256 + threadIdx.x;   // 4*512*128 elems
  short h, l;
  bsplit(W[i], h, l);
  hi[i] = h; lo[i] = l;
}

// ---------------- embeddings ----------------
__global__ void embed3_kernel(const int* __restrict__ a_ids, const int* __restrict__ d_ids,
                              const int* __restrict__ a2_ids,
                              const float* __restrict__ ea, const float* __restrict__ ed,
                              const float* __restrict__ ea2,
                              float* __restrict__ ha, float* __restrict__ hd,
                              float* __restrict__ hg2) {
  int idx = blockIdx.x*256 + threadIdx.x;
  int n = idx >> 7, j = idx & 127;
  int w = blockIdx.y;
  if (w == 0)      ha[idx]  = ea[(size_t)a_ids[n]*128 + j];
  else if (w == 1) hd[idx]  = ed[(size_t)d_ids[n]*128 + j];
  else             hg2[idx] = ea2[(size_t)a2_ids[n]*128 + j];
}

// ---------------- generic GEMM: C = act(A @ W^T + bias + beta*C) ----------------
template<int BN, int ACT>
__global__ __launch_bounds__(256) void gemm_nt(
    const float* __restrict__ A0, const float* __restrict__ A1,
    const float* __restrict__ A2, const float* __restrict__ A3,
    int lda, const float* __restrict__ WT, const float* __restrict__ bias,
    float* __restrict__ C, int K, int beta)
{
  extern __shared__ float sm[];
  const int KP = K + 4;
  float* At = sm;             // [32][KP]
  float* Bc = sm + 32*KP;     // [16][BN]
  const int tid = threadIdx.x;
  const int m0 = blockIdx.x*32;
  const int ng = tid >> 5, cg = tid & 31;
  const int n0 = ng*4, c4 = cg*4;
  constexpr int G = BN/128;
  float acc[G][4][4];
#pragma unroll
  for (int g=0; g<G; ++g)
#pragma unroll
    for (int i=0;i<4;++i)
#pragma unroll
      for (int e=0;e<4;++e) acc[g][i][e] = 0.0f;

  const int nf4 = K >> 2;
  for (int idx = tid; idx < 32*nf4; idx += 256) {
    int row = idx / nf4;
    int kk = (idx - row*nf4) << 2;
    const float* Ap = (kk < 128) ? A0 : (kk < 256) ? A1 : (kk < 384) ? A2 : A3;
    float4 v = *(const float4*)(Ap + (size_t)(m0+row)*lda + (kk & 127));
    *(float4*)(At + row*KP + kk) = v;
  }
  const int nchunk = K >> 4;
  for (int kc = 0; kc < nchunk; ++kc) {
    __syncthreads();
    for (int idx = tid; idx < 16*(BN/4); idx += 256) {
      int kk = idx / (BN/4);
      int jq = idx - kk*(BN/4);
      *(float4*)(Bc + kk*BN + jq*4) = *(const float4*)(WT + (size_t)(kc*16+kk)*BN + jq*4);
    }
    __syncthreads();
    for (int k=0;k<16;++k) {
      const int kk = kc*16 + k;
      float av[4];
#pragma unroll
      for (int i=0;i<4;++i) av[i] = At[(n0+i)*KP + kk];
#pragma unroll
      for (int g=0; g<G; ++g) {
        float4 bv = *(const float4*)(Bc + k*BN + g*128 + c4);
        float bb[4] = {bv.x, bv.y, bv.z, bv.w};
#pragma unroll
        for (int i=0;i<4;++i)
#pragma unroll
          for (int e=0;e<4;++e)
            acc[g][i][e] += av[i]*bb[e];
      }
    }
  }
#pragma unroll
  for (int g=0; g<G; ++g) {
#pragma unroll
    for (int i=0;i<4;++i) {
      float* dst = C + (size_t)(m0+n0+i)*BN + g*128 + c4;
      float o[4];
#pragma unroll
      for (int e=0;e<4;++e) o[e] = acc[g][i][e];
      if (bias) {
#pragma unroll
        for (int e=0;e<4;++e) o[e] += bias[g*128 + c4 + e];
      }
      if (beta) {
        float4 p = *(const float4*)dst;
        o[0]+=p.x; o[1]+=p.y; o[2]+=p.z; o[3]+=p.w;
      }
      if (ACT==1) {
#pragma unroll
        for (int e=0;e<4;++e) o[e] = fmaxf(o[e], 0.0f);
      }
      *(float4*)dst = make_float4(o[0],o[1],o[2],o[3]);
    }
  }
}

// ---------------- Gx precompute via MFMA, output fp16 lane-permuted ----------------
// Row layout (halfs, stride 512): half_idx = (wR*4+lq)*32 + g*8 + p*4 + e,
// where wR in 0..3, p in 0..1 are the READER's wave/half split (writer wave
// w' in 0..7 maps wR = w'>>1, p = w'&1). Reader lane (wR,lq) then loads its 32
// halfs as 4 contiguous 16B chunks.
__global__ __launch_bounds__(512) void gx_kernel(
    unsigned short* __restrict__ GxH, const float* __restrict__ fs,
    const short* __restrict__ WIhi, const short* __restrict__ WIlo,
    const float* __restrict__ bsum)
{
  __shared__ short xhi[64*136];
  __shared__ short xlo[64*136];
  const int tid = threadIdx.x;
  const int w = tid >> 6;          // writer wave 0..7
  const int lane = tid & 63;
  const int ln16 = lane & 15;
  const int lq = lane >> 4;
  const int rb = blockIdx.x * 64;

  {
    const int r = tid >> 3;
    const int cf = (tid & 7) * 16;
    const float* src = fs + (size_t)(rb + r)*128 + cf;
    short* dh = xhi + r*136 + cf;
    short* dl = xlo + r*136 + cf;
#pragma unroll
    for (int q=0; q<4; ++q) {
      float4 v = *(const float4*)(src + q*4);
      float vs[4] = {v.x, v.y, v.z, v.w};
      bf16x4 sh, sl;
#pragma unroll
      for (int e=0;e<4;++e){ short h_,l_; bsplit(vs[e],h_,l_); sh[e]=h_; sl[e]=l_; }
      *(bf16x4*)(dh + q*4) = sh;
      *(bf16x4*)(dl + q*4) = sl;
    }
  }
  f32x4 acc[4][4];   // [gate][nt]
#pragma unroll
  for (int g=0; g<4; ++g) {
    f32x4 bv = *(const f32x4*)(bsum + g*128 + w*16 + lq*4);
#pragma unroll
    for (int nt=0; nt<4; ++nt) acc[g][nt] = bv;
  }
  __syncthreads();

#pragma unroll
  for (int kt=0; kt<4; ++kt) {
    const int bo = kt*32 + lq*8;
    bf16x8 bxh[4], bxl[4];
#pragma unroll
    for (int nt=0; nt<4; ++nt) {
      bxh[nt] = *(const bf16x8*)(xhi + (nt*16+ln16)*136 + bo);
      bxl[nt] = *(const bf16x8*)(xlo + (nt*16+ln16)*136 + bo);
    }
#pragma unroll
    for (int g=0; g<4; ++g) {
      const int co = (g*128 + w*16 + ln16)*128 + kt*32 + lq*8;
      bf16x8 ah = *(const bf16x8*)(WIhi + co);
      bf16x8 al = *(const bf16x8*)(WIlo + co);
#pragma unroll
      for (int nt=0; nt<4; ++nt) {
        acc[g][nt] = __builtin_amdgcn_mfma_f32_16x16x32_bf16(ah, bxh[nt], acc[g][nt], 0,0,0);
        acc[g][nt] = __builtin_amdgcn_mfma_f32_16x16x32_bf16(ah, bxl[nt], acc[g][nt], 0,0,0);
        acc[g][nt] = __builtin_amdgcn_mfma_f32_16x16x32_bf16(al, bxh[nt], acc[g][nt], 0,0,0);
      }
    }
  }
  // permuted fp16 write
  const int lbase = ((w>>1)*4 + lq)*32 + (w&1)*4;
#pragma unroll
  for (int nt=0; nt<4; ++nt) {
    unsigned short* rowp = GxH + (size_t)(rb + nt*16 + ln16)*512 + lbase;
#pragma unroll
    for (int g=0; g<4; ++g) {
      f32x4 v = acc[g][nt];
      u16x4 pk;
#pragma unroll
      for (int e=0; e<4; ++e)
        pk[e] = __half_as_ushort(__float2half_rn(v[e]));
      *(u16x4*)(rowp + g*8) = pk;
    }
  }
}

// ---------------- LSTM recurrence (fp16 permuted Gx gather) ----------------
// 1024 blocks x 32 nodes, 4 waves. Per row a lane loads 4x16B contiguous
// (64B/lane, 256B/row/wave) -> 8 lines/row vs 16, 8 VMEM inst/lane vs 16.
__global__ __launch_bounds__(256) void lstm_seq_kernel(
    float* __restrict__ hL, const unsigned short* __restrict__ GxH,
    const int* __restrict__ nbr,
    const short* __restrict__ WHhi, const short* __restrict__ WHlo)
{
  __shared__ short hhi[32*136];
  __shared__ short hlo[32*136];
  const int tid = threadIdx.x;
  const int w = tid >> 6;          // wave 0..3
  const int lane = tid & 63;
  const int ln16 = lane & 15;
  const int lq = lane >> 4;
  const int nb = blockIdx.x * 32;
  const int lbase = (w*4 + lq)*32;

  u16x8 gxq[4][2];      // [gate][row] packed fp16 (p0 e0..3 | p1 e0..3)
  f32x4 cst[2][2];
#pragma unroll
  for (int p=0;p<2;++p)
#pragma unroll
    for (int nt=0;nt<2;++nt)
#pragma unroll
      for (int e=0;e<4;++e) cst[p][nt][e] = 0.0f;

  const int* nrow0 = nbr + (size_t)(nb + ln16)*DD;
  const int* nrow1 = nbr + (size_t)(nb + 16 + ln16)*DD;
  int gidx0 = nrow0[0], gidx1 = nrow1[0];

#pragma unroll 1
  for (int t=0; t<16; ++t) {
    // ---- (1) issue gathers (independent of MFMA chain) ----
    {
      const unsigned short* r0 = GxH + (size_t)gidx0*512 + lbase;
      const unsigned short* r1 = GxH + (size_t)gidx1*512 + lbase;
#pragma unroll
      for (int g=0; g<4; ++g) {
        gxq[g][0] = *(const u16x8*)(r0 + g*8);
        gxq[g][1] = *(const u16x8*)(r1 + g*8);
      }
    }
    if (t < 15) { gidx0 = nrow0[t+1]; gidx1 = nrow1[t+1]; }

    // ---- (2) recurrent term into zero-init racc ----
    f32x4 racc[4][2][2];
#pragma unroll
    for (int g=0;g<4;++g)
#pragma unroll
      for (int p=0;p<2;++p)
#pragma unroll
        for (int nt=0;nt<2;++nt)
#pragma unroll
          for (int e=0;e<4;++e) racc[g][p][nt][e] = 0.0f;
    if (t > 0) {
#pragma unroll
      for (int kt=0; kt<4; ++kt) {
        const int bo = kt*32 + lq*8;
        bf16x8 bh[2], bl[2];
#pragma unroll
        for (int nt=0; nt<2; ++nt) {
          bh[nt] = *(const bf16x8*)(hhi + (nt*16+ln16)*136 + bo);
          bl[nt] = *(const bf16x8*)(hlo + (nt*16+ln16)*136 + bo);
        }
#pragma unroll
        for (int g=0; g<4; ++g) {
#pragma unroll
          for (int p=0; p<2; ++p) {
            const int co = (g*128 + w*32 + p*16 + ln16)*128 + kt*32 + lq*8;
            bf16x8 ah = *(const bf16x8*)(WHhi + co);
            bf16x8 al = *(const bf16x8*)(WHlo + co);
#pragma unroll
            for (int nt=0; nt<2; ++nt) {
              racc[g][p][nt] = __builtin_amdgcn_mfma_f32_16x16x32_bf16(ah, bh[nt], racc[g][p][nt], 0,0,0);
              racc[g][p][nt] = __builtin_amdgcn_mfma_f32_16x16x32_bf16(ah, bl[nt], racc[g][p][nt], 0,0,0);
              racc[g][p][nt] = __builtin_amdgcn_mfma_f32_16x16x32_bf16(al, bh[nt], racc[g][p][nt], 0,0,0);
            }
          }
        }
      }
    }
    __syncthreads();   // all h(t-1) LDS reads done (WAR)

    // ---- (3) activations: pre = half2float(gx) + racc ----
#pragma unroll
    for (int p=0; p<2; ++p) {
#pragma unroll
      for (int nt=0; nt<2; ++nt) {
        float hv[4];
#pragma unroll
        for (int e=0; e<4; ++e) {
          float ig = fsig(__half2float(__ushort_as_half(gxq[0][nt][p*4+e])) + racc[0][p][nt][e]);
          float fg = fsig(__half2float(__ushort_as_half(gxq[1][nt][p*4+e])) + racc[1][p][nt][e]);
          float gg = ftanh(__half2float(__ushort_as_half(gxq[2][nt][p*4+e])) + racc[2][p][nt][e]);
          float og = fsig(__half2float(__ushort_as_half(gxq[3][nt][p*4+e])) + racc[3][p][nt][e]);
          float cc = fg*cst[p][nt][e] + ig*gg;
          cst[p][nt][e] = cc;
          hv[e] = og*ftanh(cc);
        }
        const int node = nt*16 + ln16;
        const int col0 = w*32 + p*16 + lq*4;
        if (t < 15) {
          bf16x4 sh, sl;
#pragma unroll
          for (int e=0; e<4; ++e) { short h_,l_; bsplit(hv[e],h_,l_); sh[e]=h_; sl[e]=l_; }
          *(bf16x4*)(hhi + node*136 + col0) = sh;
          *(bf16x4*)(hlo + node*136 + col0) = sl;
        } else {
          *(float4*)(hL + (size_t)(nb + node)*128 + col0) =
              make_float4(hv[0], hv[1], hv[2], hv[3]);
        }
      }
    }
    __syncthreads();   // h(t) writes visible before next step's reads (RAW)
  }
}

// ---------------- GGC scatter-add: a[dst] += m[src] (128 floats/edge) ----------------
__global__ void scatter_add_kernel(float* __restrict__ a, const float* __restrict__ m,
                                   const int* __restrict__ src, const int* __restrict__ dst) {
  int wid = (blockIdx.x*256 + threadIdx.x) >> 6;
  int lane = threadIdx.x & 63;
  int s = src[wid], d = dst[wid];
  const float* mr = m + (size_t)s*128;
  float* ar = a + (size_t)d*128;
  atomicAdd(ar + lane, mr[lane]);
  atomicAdd(ar + 64 + lane, mr[64 + lane]);
}

// ---------------- GRU pointwise ----------------
__global__ void gru_update_kernel(float* __restrict__ hh, const float* __restrict__ gi,
                                  const float* __restrict__ gh) {
  int idx = blockIdx.x*256 + threadIdx.x;
  int n = idx >> 7, j = idx & 127;
  const float* gin = gi + (size_t)n*384;
  const float* ghn = gh + (size_t)n*384;
  float r  = fsig(gin[j] + ghn[j]);
  float z  = fsig(gin[128+j] + ghn[128+j]);
  float nn2 = ftanh(gin[256+j] + r*ghn[256+j]);
  float h = hh[idx];
  hh[idx] = (1.0f - z)*nn2 + z*h;
}

// ---------------- LayerNorm (+optional residual add) + leaky relu ----------------
__global__ void ln_lrelu_kernel(float* __restrict__ out, const float* __restrict__ x,
                                const float* __restrict__ add,
                                const float* __restrict__ g, const float* __restrict__ b) {
  int n = blockIdx.x, j = threadIdx.x;   // 128 threads
  size_t base = (size_t)n*128;
  float v = x[base+j];
  if (add) v += add[base+j];
  __shared__ float sh[4];
  float s = v;
#pragma unroll
  for (int m=32; m>=1; m>>=1) s += __shfl_xor(s, m, 64);
  if ((j&63)==0) sh[j>>6] = s;
  __syncthreads();
  float mean = (sh[0]+sh[1]) * 0.0078125f;
  float d = v - mean;
  float q = d*d;
#pragma unroll
  for (int m=32; m>=1; m>>=1) q += __shfl_xor(q, m, 64);
  if ((j&63)==0) sh[2+(j>>6)] = q;
  __syncthreads();
  float var = (sh[2]+sh[3]) * 0.0078125f;
  float y = d * rsqrtf(var + 1e-5f) * g[j] + b[j];
  out[base+j] = (y >= 0.0f) ? y : 0.01f*y;
}

// ---------------- segment mean (contiguous 128-node segments) ----------------
__global__ void segmean_kernel(float* __restrict__ out, const float* __restrict__ x,
                               const float* __restrict__ y) {
  int b = blockIdx.x, j = threadIdx.x;   // 128 threads, 256 blocks
  float s = 0.0f;
  for (int r=0; r<128; ++r) {
    size_t n = (size_t)(b*128 + r)*128 + j;
    s += x[n];
    if (y) s += y[n];
  }
  out[(size_t)b*128 + j] = s * 0.0078125f;
}

// ---------------- classifier head ----------------
__global__ void cls_kernel(float* __restrict__ out, const float* __restrict__ h2,
                           const float* __restrict__ Wc, const float* __restrict__ bc) {
  int gid = blockIdx.x*256 + threadIdx.x;
  if (gid >= BB*10) return;
  int mrow = gid/10, c = gid - mrow*10;
  const float* arow = h2 + (size_t)mrow*128;
  const float* wrow = Wc + (size_t)c*128;
  float s = bc[c];
  for (int k=0;k<128;++k) s += arow[k]*wrow[k];
  out[gid] = s;
}

__global__ void bail_kernel(float* out, float v) {
  if (threadIdx.x==0 && blockIdx.x==0) out[0] = v;
}

// ---------------- host orchestration ----------------
extern "C" void kernel_launch(void* const* d_in, const int* in_sizes, int n_in,
                              void* d_out, int out_size, void* d_ws, size_t ws_size,
                              hipStream_t stream)
{
  const int* act_ids  = (const int*)d_in[0];
  const int* dur_ids  = (const int*)d_in[1];
  const int* act2_ids = (const int*)d_in[2];
  const int* nbr_a2d  = (const int*)d_in[3];
  const int* nbr_d2a  = (const int*)d_in[4];
  const int* src2     = (const int*)d_in[5];
  const int* dst2     = (const int*)d_in[6];
  const float* emb_act     = (const float*)d_in[8];
  const float* emb_dur     = (const float*)d_in[9];
  const float* emb_act2    = (const float*)d_in[10];
  const float* transform_W = (const float*)d_in[11];
  const float* transform_b = (const float*)d_in[12];
  const float* ggc_W   = (const float*)d_in[13];
  const float* ggc_b   = (const float*)d_in[14];
  const float* gru_Wih = (const float*)d_in[15];
  const float* gru_Whh = (const float*)d_in[16];
  const float* gru_bih = (const float*)d_in[17];
  const float* gru_bhh = (const float*)d_in[18];
  const float* hn_g    = (const float*)d_in[19];
  const float* hn_b    = (const float*)d_in[20];
  const float* lstm_Wih = (const float*)d_in[21];
  const float* lstm_Whh = (const float*)d_in[22];
  const float* lstm_bih = (const float*)d_in[23];
  const float* lstm_bhh = (const float*)d_in[24];
  const float* fcs_W = (const float*)d_in[25];
  const float* fcs_b = (const float*)d_in[26];
  const float* fcn_W = (const float*)d_in[27];
  const float* fcn_b = (const float*)d_in[28];
  const float* n1_g = (const float*)d_in[29];
  const float* n1_b = (const float*)d_in[30];
  const float* n3_g = (const float*)d_in[31];
  const float* n3_b = (const float*)d_in[32];
  const float* mh_W1 = (const float*)d_in[33];
  const float* mh_b1 = (const float*)d_in[34];
  const float* mh_W2 = (const float*)d_in[35];
  const float* mh_b2 = (const float*)d_in[36];
  const float* mo_W1 = (const float*)d_in[37];
  const float* mo_b1 = (const float*)d_in[38];
  const float* mo_W2 = (const float*)d_in[39];
  const float* mo_b2 = (const float*)d_in[40];
  const float* mlp_W1 = (const float*)d_in[41];
  const float* mlp_b1 = (const float*)d_in[42];
  const float* mlp_W2 = (const float*)d_in[43];
  const float* mlp_b2 = (const float*)d_in[44];
  const float* cls_W = (const float*)d_in[45];
  const float* cls_b = (const float*)d_in[46];

  float* ws = (float*)d_ws;
  float* ha   = ws;
  float* hd   = ws + (size_t)NF;
  float* hg2  = ws + 2*(size_t)NF;
  float* res  = ws + 3*(size_t)NF;
  float* hh   = ws + 4*(size_t)NF;
  float* SCR  = ws + 5*(size_t)NF;
  float* mb   = SCR;
  float* abuf = SCR + (size_t)NF;
  float* gi   = SCR + 2*(size_t)NF;
  float* gh   = SCR + 5*(size_t)NF;
  float* hnf  = mb;
  float* Gx   = SCR;                       // fp16 [N][512] = 2*NF floats worth
  float* hLb  = SCR + 8*(size_t)NF;
  float* SMALL = ws + 15*(size_t)NF;
  float* hg2m = SMALL;
  float* hgm  = SMALL + 32768;
  float* o1b  = SMALL + 65536;
  float* o2b  = SMALL + 98304;
  float* t1b  = SMALL + 131072;
  float* t2b  = SMALL + 163840;
  float* h1b  = SMALL + 196608;
  float* h2b  = SMALL + 262144;
  float* bsum = SMALL + 294912;
  float* WTb  = SMALL + 296960;
  const size_t NEED_BYTES = (size_t)(15*(size_t)NF + 296960 + 1032192) * 4;
  if (ws_size < NEED_BYTES) {
    hipMemsetAsync(d_out, 0, (size_t)out_size*sizeof(float), stream);
    bail_kernel<<<1,64,0,stream>>>((float*)d_out, (float)ws_size);
    return;
  }
  float* na = hg2;
  float* nd = res;
  unsigned short* GxH = (unsigned short*)Gx;

  const int O_TRANSFORM = 0;
  const int O_GGC      = 32768;
  const int O_GRUWIH   = 49152;
  const int O_GRUWHH   = 98304;
  const int O_SPLIT    = 147456;
  const int O_FCS      = 671744;
  const int O_FCN      = 737280;
  const int O_MH1      = 802816;
  const int O_MH2      = 819200;
  const int O_MO1      = 835584;
  const int O_MO2      = 851968;
  const int O_MLP1     = 868352;
  const int O_MLP2     = 999424;

  short* SPL = (short*)(WTb + O_SPLIT);
  short* WIhi = SPL;
  short* WIlo = SPL + 4*65536;
  short* WHhi = SPL + 8*65536;
  short* WHlo = SPL + 12*65536;

  TDescArr da;
  int di = 0;
  auto addT = [&](const float* s, float* d, int R, int C){ da.d[di].src=s; da.d[di].dst=d; da.d[di].R=R; da.d[di].C=C; ++di; };
  addT(transform_W, WTb + O_TRANSFORM, 128, 256);
  addT(ggc_W,   WTb + O_GGC,    128, 128);
  addT(gru_Wih, WTb + O_GRUWIH, 384, 128);
  addT(gru_Whh, WTb + O_GRUWHH, 384, 128);
  for (int i=0;i<4;++i) addT(fcs_W + (size_t)i*16384, WTb + O_FCS + i*16384, 128, 128);
  for (int i=0;i<4;++i) addT(fcn_W + (size_t)i*16384, WTb + O_FCN + i*16384, 128, 128);
  addT(mh_W1, WTb + O_MH1, 128, 128);
  addT(mh_W2, WTb + O_MH2, 128, 128);
  addT(mo_W1, WTb + O_MO1, 128, 128);
  addT(mo_W2, WTb + O_MO2, 128, 128);
  addT(mlp_W1, WTb + O_MLP1, 256, 512);
  addT(mlp_W2, WTb + O_MLP2, 128, 256);
  transpose_many<<<dim3(512, di), 256, 0, stream>>>(da);
  bias_sum_kernel<<<8, 256, 0, stream>>>(lstm_bih, lstm_bhh, bsum);
  wsplit_kernel<<<(4*512*128)/256, 256, 0, stream>>>(lstm_Wih, WIhi, WIlo);
  wsplit_kernel<<<(4*512*128)/256, 256, 0, stream>>>(lstm_Whh, WHhi, WHlo);

  auto smemK = [](int K, int BN){ return (size_t)(32*(K+4) + 16*BN)*4; };
  const int gN = NN/32;
  const int gB = BB/32;

  embed3_kernel<<<dim3(NF/256, 3), 256, 0, stream>>>(act_ids, dur_ids, act2_ids,
      emb_act, emb_dur, emb_act2, ha, hd, hg2);
  gemm_nt<128,0><<<gN, 256, smemK(256,128), stream>>>(hg2, hd, nullptr, nullptr, 128,
      WTb + O_TRANSFORM, transform_b, res, 256, 0);
  hipMemcpyAsync(hh, res, (size_t)NF*4, hipMemcpyDeviceToDevice, stream);

  for (int it=0; it<2; ++it) {
    gemm_nt<128,0><<<gN, 256, smemK(128,128), stream>>>(hh, nullptr, nullptr, nullptr, 128,
        WTb + O_GGC, ggc_b, mb, 128, 0);
    hipMemsetAsync(abuf, 0, (size_t)NF*4, stream);
    scatter_add_kernel<<<E2N/4, 256, 0, stream>>>(abuf, mb, src2, dst2);
    gemm_nt<384,0><<<gN, 256, smemK(128,384), stream>>>(abuf, nullptr, nullptr, nullptr, 128,
        WTb + O_GRUWIH, gru_bih, gi, 128, 0);
    gemm_nt<384,0><<<gN, 256, smemK(128,384), stream>>>(hh, nullptr, nullptr, nullptr, 128,
        WTb + O_GRUWHH, gru_bhh, gh, 128, 0);
    gru_update_kernel<<<NF/256, 256, 0, stream>>>(hh, gi, gh);
  }
  ln_lrelu_kernel<<<NN, 128, 0, stream>>>(hnf, hh, res, hn_g, hn_b);
  segmean_kernel<<<BB, 128, 0, stream>>>(hg2m, hnf, nullptr);

  for (int l=0; l<2; ++l) {
    const int i0 = l*2 + 0, i1 = l*2 + 1;
    gx_kernel<<<512, 512, 0, stream>>>(GxH, ha,
        WIhi + i0*65536, WIlo + i0*65536, bsum + i0*512);
    lstm_seq_kernel<<<1024, 256, 0, stream>>>(hLb, GxH, nbr_a2d,
        WHhi + i0*65536, WHlo + i0*65536);
    gx_kernel<<<512, 512, 0, stream>>>(GxH, hd,
        WIhi + i1*65536, WIlo + i1*65536, bsum + i1*512);
    lstm_seq_kernel<<<1024, 256, 0, stream>>>(hLb + (size_t)NN*128, GxH, nbr_d2a,
        WHhi + i1*65536, WHlo + i1*65536);

    gemm_nt<128,0><<<gN, 256, smemK(128,128), stream>>>(hd, nullptr, nullptr, nullptr, 128,
        WTb + O_FCS + i0*16384, fcs_b + i0*128, nd, 128, 0);
    gemm_nt<128,0><<<gN, 256, smemK(128,128), stream>>>(hLb, nullptr, nullptr, nullptr, 128,
        WTb + O_FCN + i0*16384, fcn_b + i0*128, nd, 128, 1);
    gemm_nt<128,0><<<gN, 256, smemK(128,128), stream>>>(ha, nullptr, nullptr, nullptr, 128,
        WTb + O_FCS + i1*16384, fcs_b + i1*128, na, 128, 0);
    gemm_nt<128,0><<<gN, 256, smemK(128,128), stream>>>(hLb + (size_t)NN*128, nullptr, nullptr, nullptr, 128,
        WTb + O_FCN + i1*16384, fcn_b + i1*128, na, 128, 1);
    ln_lrelu_kernel<<<NN, 128, 0, stream>>>(na, na, nullptr, n1_g + i0*128, n1_b + i0*128);
    ln_lrelu_kernel<<<NN, 128, 0, stream>>>(nd, nd, nullptr, n1_g + i1*128, n1_b + i1*128);
    ln_lrelu_kernel<<<NN, 128, 0, stream>>>(ha, ha, na, n3_g + i0*128, n3_b + i0*128);
    ln_lrelu_kernel<<<NN, 128, 0, stream>>>(hd, hd, nd, n3_g + i1*128, n3_b + i1*128);
  }
  segmean_kernel<<<BB, 128, 0, stream>>>(hgm, ha, hd);

  gemm_nt<128,1><<<gB, 256, smemK(128,128), stream>>>(hg2m, nullptr, nullptr, nullptr, 128,
      WTb + O_MO1, mo_b1, t1b, 128, 0);
  gemm_nt<128,1><<<gB, 256, smemK(128,128), stream>>>(t1b, nullptr, nullptr, nullptr, 128,
      WTb + O_MO2, mo_b2, o1b, 128, 0);
  gemm_nt<128,1><<<gB, 256, smemK(128,128), stream>>>(hgm, nullptr, nullptr, nullptr, 128,
      WTb + O_MH1, mh_b1, t2b, 128, 0);
  gemm_nt<128,1><<<gB, 256, smemK(128,128), stream>>>(t2b, nullptr, nullptr, nullptr, 128,
      WTb + O_MH2, mh_b2, o2b, 128, 0);
  gemm_nt<256,0><<<gB, 256, smemK(256,256), stream>>>(o1b, hg2m, nullptr, nullptr, 128,
      WTb + O_MLP1, nullptr, h1b, 256, 0);
  gemm_nt<256,1><<<gB, 256, smemK(256,256), stream>>>(o2b, hgm, nullptr, nullptr, 128,
      WTb + O_MLP1 + 256*256, mlp_b1, h1b, 256, 1);
  gemm_nt<128,1><<<gB, 256, smemK(256,128), stream>>>(h1b, h1b + 128, nullptr, nullptr, 256,
      WTb + O_MLP2, mlp_b2, h2b, 256, 0);
  cls_kernel<<<10, 256, 0, stream>>>((float*)d_out, h2b, cls_W, cls_b);
}